// Round 11
// baseline (574.743 us; speedup 1.0000x reference)
//
#include <hip/hip_runtime.h>
#include <stdint.h>

// Triaffine: out[b,z,x,y] = sum_{i,j,k} xb[x,i] z[z,k] W[i,k,j] yb[y,j]
// B=4, S=128, D=512.  W: [513][512][513] f32 (i,k,j), elem (i,k,j) at (i*512+k)*513+j.
//
//   M[bz,i,j] = sum_k z[bz,k] W[i,k,j]        (i,j < 512)   -- k_gemm1 (8-phase), bf16
//   per bz:  R[i,y] = sum_j M[i,j] Ybf[y,j]                  -- k_fuse pass-2
//            out[x,y] = sum_i Xbf[x,i] R[i,y] + u[x]+v[y]+d  -- k_fuse pass-3
//   a[bz,i], c[bz,j], d[bz] from W edges (k_edge); u=x.a, v=y.c (k_uv)

typedef __attribute__((ext_vector_type(8))) short bf16x8;
typedef __attribute__((ext_vector_type(4))) float f32x4;

__device__ __forceinline__ unsigned short f2bf(float f) {
    unsigned int u = __float_as_uint(f);
    u += 0x7fffu + ((u >> 16) & 1u);      // RNE
    return (unsigned short)(u >> 16);
}

__device__ __forceinline__ void gload_lds16(const void* g, void* l) {
    __builtin_amdgcn_global_load_lds((const __attribute__((address_space(1))) void*)g,
                                     (__attribute__((address_space(3))) void*)l, 16, 0, 0);
}

// ---------------- cast x,y,z -> bf16 ----------------
__global__ __launch_bounds__(256) void k_cast(const float* __restrict__ x,
    const float* __restrict__ y, const float* __restrict__ z,
    unsigned short* __restrict__ xbf, unsigned short* __restrict__ ybf,
    unsigned short* __restrict__ zbf)
{
    int t = blockIdx.x * 256 + threadIdx.x;
    int arr = t >> 15;
    int off = (t & 32767) * 8;
    const float* src = (arr == 0) ? x : (arr == 1) ? y : z;
    unsigned short* dst = (arr == 0) ? xbf : (arr == 1) ? ybf : zbf;
    float4 a = *(const float4*)(src + off);
    float4 b = *(const float4*)(src + off + 4);
    uint4 o;
    o.x = f2bf(a.x) | ((unsigned)f2bf(a.y) << 16);
    o.y = f2bf(a.z) | ((unsigned)f2bf(a.w) << 16);
    o.z = f2bf(b.x) | ((unsigned)f2bf(b.y) << 16);
    o.w = f2bf(b.z) | ((unsigned)f2bf(b.w) << 16);
    *(uint4*)(dst + off) = o;
}

// ---------------- bias-edge GEMMs ----------------
__global__ __launch_bounds__(256) void k_edge(const float* __restrict__ z,
    const float* __restrict__ w, float* __restrict__ a_arr,
    float* __restrict__ c_arr, float* __restrict__ d_arr)
{
    __shared__ float Zs[64][33];
    __shared__ float Bs[32][65];
    int t = threadIdx.x;
    int mb = blockIdx.x % 17, bzb = blockIdx.x / 17;
    int tr = t >> 4, tc = t & 15;
    float acc[4][4] = {};
    for (int k0 = 0; k0 < 512; k0 += 32) {
        __syncthreads();
        {   int row = t >> 2, ko = (t & 3) * 8;
            const float* p = z + (bzb * 64 + row) * 512 + k0 + ko;
            float4 v0 = ((const float4*)p)[0], v1 = ((const float4*)p)[1];
            Zs[row][ko + 0] = v0.x; Zs[row][ko + 1] = v0.y; Zs[row][ko + 2] = v0.z; Zs[row][ko + 3] = v0.w;
            Zs[row][ko + 4] = v1.x; Zs[row][ko + 5] = v1.y; Zs[row][ko + 6] = v1.z; Zs[row][ko + 7] = v1.w;
        }
        {   int kr = t >> 3, mo = (t & 7) * 8;
            for (int e = 0; e < 8; ++e) {
                int m = mb * 64 + mo + e;
                float v = 0.f;
                int krow = k0 + kr;
                if (m < 512)        v = w[(m * 512 + krow) * 513 + 512];
                else if (m < 1024)  v = w[(262144 + krow) * 513 + (m - 512)];
                else if (m == 1024) v = w[(262144 + krow) * 513 + 512];
                Bs[kr][mo + e] = v;
            }
        }
        __syncthreads();
        for (int kk = 0; kk < 32; ++kk) {
            float zr[4], br[4];
            for (int r = 0; r < 4; ++r) zr[r] = Zs[tr * 4 + r][kk];
            for (int c = 0; c < 4; ++c) br[c] = Bs[kk][tc * 4 + c];
            for (int r = 0; r < 4; ++r)
                for (int c = 0; c < 4; ++c) acc[r][c] += zr[r] * br[c];
        }
    }
    for (int r = 0; r < 4; ++r)
        for (int c = 0; c < 4; ++c) {
            int bz = bzb * 64 + tr * 4 + r;
            int m = mb * 64 + tc * 4 + c;
            if (m < 512)        a_arr[bz * 512 + m] = acc[r][c];
            else if (m < 1024)  c_arr[bz * 512 + (m - 512)] = acc[r][c];
            else if (m == 1024) d_arr[bz] = acc[r][c];
        }
}

// ---------------- k_uv: u[bz,x] = x.a_bz, v[bz,y] = y.c_bz ----------------
__global__ __launch_bounds__(512) void k_uv(const float* __restrict__ xf,
    const float* __restrict__ yf, const float* __restrict__ a_arr,
    const float* __restrict__ c_arr, float* __restrict__ u_arr,
    float* __restrict__ v_arr)
{
    __shared__ float part[512];
    int bz = blockIdx.x;
    int b = bz >> 7;
    int t = threadIdx.x, r = t >> 2, q = t & 3;
    {
        const float* xp = xf + (size_t)(b * 128 + r) * 512;
        const float* ap = a_arr + bz * 512;
        float s = 0.f;
        #pragma unroll 4
        for (int c0 = 0; c0 < 32; ++c0) {
            int col = c0 * 16 + q * 4;
            float4 xv = *(const float4*)(xp + col);
            float4 av = *(const float4*)(ap + col);
            s += xv.x * av.x + xv.y * av.y + xv.z * av.z + xv.w * av.w;
        }
        part[t] = s;
    }
    __syncthreads();
    if (t < 128) u_arr[bz * 128 + t] = part[t*4] + part[t*4+1] + part[t*4+2] + part[t*4+3];
    __syncthreads();
    {
        const float* yp = yf + (size_t)(b * 128 + r) * 512;
        const float* cp = c_arr + bz * 512;
        float s = 0.f;
        #pragma unroll 4
        for (int c0 = 0; c0 < 32; ++c0) {
            int col = c0 * 16 + q * 4;
            float4 yv = *(const float4*)(yp + col);
            float4 cv = *(const float4*)(cp + col);
            s += yv.x * cv.x + yv.y * cv.y + yv.z * cv.z + yv.w * cv.w;
        }
        part[t] = s;
    }
    __syncthreads();
    if (t < 128) v_arr[bz * 128 + t] = part[t*4] + part[t*4+1] + part[t*4+2] + part[t*4+3];
}

// ---------------- G1 v6: m201-style 8-phase 256x256x64 GEMM ----------------
// A = Z [512 bz x 512 k] bf16 (gload_lds, pre-swizzled src); B = W panel
// [512 k x 256 j] f32 -> reg-staged bf16 (T14 issue-early/pack-late).
// 2048 WGs = 1024 panels(i,jhalf) x 2 bz-tiles, pair-ordered + chunked XCD
// swizzle (pair shares W panel via same-XCD L2). 8 waves (2M x 4N), wave tile
// 128x64, acc[8][4]. 8 K-tiles of 64; 4 phases each: quadrant MFMA x16 between
// s_barrier/lgkmcnt(0)/setprio brackets; LDS 128 KB dbuf, XOR chunk^=(row&7).
__global__ __launch_bounds__(512, 2) void k_gemm1(const unsigned short* __restrict__ zbf,
    const float* __restrict__ w, unsigned short* __restrict__ Mws)
{
    extern __shared__ unsigned char smem[];
    unsigned char* const Ab0 = smem;            // [256 bz][64 k] bf16 = 32 KB
    unsigned char* const Ab1 = smem + 32768;
    unsigned char* const Bb0 = smem + 65536;    // [256 j][64 k] bf16 = 32 KB
    unsigned char* const Bb1 = smem + 98304;    // total 131072

    int bid = blockIdx.x;
    int swz = (bid & 7) * 256 + (bid >> 3);     // chunked XCD swizzle (2048 % 8 == 0)
    int mt2 = swz & 1;                          // bz-tile (pair member)
    int panel = swz >> 1;
    int jb = panel & 1, iw = panel >> 1;
    int bz0 = mt2 * 256;
    int jlo = jb * 256;
    int t = threadIdx.x, wid = t >> 6, lane = t & 63;
    int wm = wid >> 2, wn = wid & 3;
    int l15 = lane & 15, l4 = lane >> 4;

    // A staging source (pre-swizzled: chunk = slot ^ (row&7))
    int ar = t >> 3;
    int ac = (t & 7) ^ (ar & 7);
    const unsigned short* zsrc = zbf + (size_t)(bz0 + ar) * 512 + ac * 8;

    // B staging: thread -> j = t&127, k-group s2 = t>>7 (16 k's)
    int jB = t & 127, s2 = t >> 7;
    const float* wsrc = w + (size_t)iw * 262656 + (size_t)(s2 * 16) * 513 + jlo + jB;
    int bw0 = jB * 128 + (((s2 * 2)     ^ (jB & 7)) * 16);
    int bw1 = jB * 128 + (((s2 * 2 + 1) ^ (jB & 7)) * 16);

    // fragment read bases
    int axr = l15 & 7;
    int abase = (wm * 128 + l15) * 128;
    int bbase = (wn * 64 + l15) * 128;

    f32x4 acc[8][4];
    #pragma unroll
    for (int f = 0; f < 8; ++f)
        #pragma unroll
        for (int g = 0; g < 4; ++g) acc[f][g] = (f32x4){0.f, 0.f, 0.f, 0.f};

    float wr0[16], wr1[16];
    bf16x8 af[4][2], bfA[2][2], bfB[2][2];

#define LDW(dst, kt, h) { const float* _p = wsrc + (size_t)(kt) * 64 * 513 + (h) * 128; \
    _Pragma("unroll") for (int _e = 0; _e < 16; ++_e) dst[_e] = _p[(size_t)_e * 513]; }

#define STAGE_A(buf, kt) { int _ko = (kt) * 64; \
    gload_lds16(zsrc + _ko,          (buf) + t * 16); \
    gload_lds16(zsrc + 32768 + _ko,  (buf) + 8192 + t * 16); \
    gload_lds16(zsrc + 65536 + _ko,  (buf) + 16384 + t * 16); \
    gload_lds16(zsrc + 98304 + _ko,  (buf) + 24576 + t * 16); }

#define PACKW(buf, half, src) { uint4 _pa, _pb; \
    _pa.x = f2bf(src[0])  | ((unsigned)f2bf(src[1])  << 16); \
    _pa.y = f2bf(src[2])  | ((unsigned)f2bf(src[3])  << 16); \
    _pa.z = f2bf(src[4])  | ((unsigned)f2bf(src[5])  << 16); \
    _pa.w = f2bf(src[6])  | ((unsigned)f2bf(src[7])  << 16); \
    _pb.x = f2bf(src[8])  | ((unsigned)f2bf(src[9])  << 16); \
    _pb.y = f2bf(src[10]) | ((unsigned)f2bf(src[11]) << 16); \
    _pb.z = f2bf(src[12]) | ((unsigned)f2bf(src[13]) << 16); \
    _pb.w = f2bf(src[14]) | ((unsigned)f2bf(src[15]) << 16); \
    *(uint4*)((buf) + (half) * 16384 + bw0) = _pa; \
    *(uint4*)((buf) + (half) * 16384 + bw1) = _pb; }

#define LD_A(buf, mq) { _Pragma("unroll") for (int _f = 0; _f < 4; ++_f) \
    _Pragma("unroll") for (int _kc = 0; _kc < 2; ++_kc) \
    af[_f][_kc] = *(const bf16x8*)((buf) + abase + ((mq) * 64 + _f * 16) * 128 \
                                   + (((_kc * 4 + l4) ^ axr) * 16)); }

#define LD_B(buf, nq, dst) { _Pragma("unroll") for (int _g = 0; _g < 2; ++_g) \
    _Pragma("unroll") for (int _kc = 0; _kc < 2; ++_kc) \
    dst[_g][_kc] = *(const bf16x8*)((buf) + bbase + ((nq) * 32 + _g * 16) * 128 \
                                    + (((_kc * 4 + l4) ^ axr) * 16)); }

#define MM(mq, nq, bfr) { _Pragma("unroll") for (int _f = 0; _f < 4; ++_f) \
    _Pragma("unroll") for (int _g = 0; _g < 2; ++_g) \
    _Pragma("unroll") for (int _kc = 0; _kc < 2; ++_kc) \
    acc[(mq) * 4 + _f][(nq) * 2 + _g] = __builtin_amdgcn_mfma_f32_16x16x32_bf16( \
        af[_f][_kc], bfr[_g][_kc], acc[(mq) * 4 + _f][(nq) * 2 + _g], 0, 0, 0); }

#define PH_SYNC() { __builtin_amdgcn_s_barrier(); \
    asm volatile("s_waitcnt lgkmcnt(0)" ::: "memory"); \
    __builtin_amdgcn_sched_barrier(0); }
#define PH_END() { __builtin_amdgcn_s_barrier(); __builtin_amdgcn_sched_barrier(0); }

    // ---- prologue: stage K-tile 0 into buf0 ----
    LDW(wr0, 0, 0);
    LDW(wr1, 0, 1);
    STAGE_A(Ab0, 0);
    PACKW(Bb0, 0, wr0);       // auto-vmcnt waits wr0 only
    PACKW(Bb0, 1, wr1);       // auto-vmcnt waits wr1
    asm volatile("s_waitcnt vmcnt(0) lgkmcnt(0)" ::: "memory");
    __builtin_amdgcn_s_barrier();
    __builtin_amdgcn_sched_barrier(0);

    #pragma unroll
    for (int kt = 0; kt < 8; ++kt) {
        unsigned char* Ac = (kt & 1) ? Ab1 : Ab0;
        unsigned char* Bc = (kt & 1) ? Bb1 : Bb0;
        unsigned char* An = (kt & 1) ? Ab0 : Ab1;
        unsigned char* Bn = (kt & 1) ? Bb0 : Bb1;

        // ---- phase 0: quadrant (mq0,nq0); issue W-half0 f32 + A glds for kt+1 ----
        LD_A(Ac, 0);
        LD_B(Bc, 0, bfA);
        if (kt < 7) { LDW(wr0, kt + 1, 0); STAGE_A(An, kt + 1); }
        PH_SYNC();
        __builtin_amdgcn_s_setprio(1);
        MM(0, 0, bfA);
        __builtin_amdgcn_s_setprio(0);
        PH_END();

        // ---- phase 1: quadrant (mq0,nq1); issue W-half1 f32 ----
        LD_B(Bc, 1, bfB);
        if (kt < 7) { LDW(wr1, kt + 1, 1); }
        PH_SYNC();
        __builtin_amdgcn_s_setprio(1);
        MM(0, 1, bfB);
        __builtin_amdgcn_s_setprio(0);
        PH_END();

        // ---- phase 2: quadrant (mq1,nq0); pack+write W-half0 ----
        LD_A(Ac, 1);
        if (kt < 7) { PACKW(Bn, 0, wr0); }   // auto vmcnt leaves A-glds+wr1 in flight
        PH_SYNC();
        __builtin_amdgcn_s_setprio(1);
        MM(1, 0, bfA);
        __builtin_amdgcn_s_setprio(0);
        PH_END();

        // ---- phase 3: quadrant (mq1,nq1); pack+write W-half1 (drains all staging) ----
        if (kt < 7) { PACKW(Bn, 1, wr1); }   // auto vmcnt(0): A-glds done too
        PH_SYNC();
        __builtin_amdgcn_s_setprio(1);
        MM(1, 1, bfB);
        __builtin_amdgcn_s_setprio(0);
        if (kt < 7) PH_END();
    }

#undef LDW
#undef STAGE_A
#undef PACKW
#undef LD_A
#undef LD_B
#undef MM
#undef PH_SYNC
#undef PH_END

    // ---- epilogue: store M[bz][iw][j] bf16 ----
    #pragma unroll
    for (int f = 0; f < 8; ++f)
        #pragma unroll
        for (int g = 0; g < 4; ++g)
            #pragma unroll
            for (int r = 0; r < 4; ++r) {
                int bz = bz0 + wm * 128 + f * 16 + l4 * 4 + r;
                int jg = jlo + wn * 64 + g * 16 + l15;
                Mws[(size_t)bz * 262144 + (size_t)iw * 512 + jg] = f2bf(acc[f][g][r]);
            }
}

// ---------------- G2 v5 (round-10 best, unchanged) ----------------
__global__ __launch_bounds__(512, 2) void k_fuse(const unsigned short* __restrict__ xbf,
    const unsigned short* __restrict__ ybf, const unsigned short* __restrict__ Mws,
    const float* __restrict__ u_arr, const float* __restrict__ v_arr,
    const float* __restrict__ d_arr, float* __restrict__ out)
{
    extern __shared__ unsigned char smem[];    // 131072: Y, later reused as R

    int bid = blockIdx.x;
    int bz = (bid & 7) * 64 + (bid >> 3);      // XCD swizzle (512 = 8*64)
    int b = bz >> 7;
    int t = threadIdx.x, wid = t >> 6, lane = t & 63;
    int l15 = lane & 15, l4 = lane >> 4;
    int xg = wid >> 2, yg = wid & 3;
    int g8 = wid;

    const unsigned short* ybase = ybf + (size_t)(b * 128) * 512;
    #pragma unroll
    for (int it = 0; it < 16; ++it) {
        int row = it * 8 + wid;
        gload_lds16(ybase + (size_t)row * 512 + ((lane ^ (row & 63)) * 8),
                    smem + it * 8192 + t * 16);
    }

    const unsigned short* mbase = Mws + (size_t)bz * 262144
                                + (size_t)(g8 * 64 + l15) * 512 + l4 * 8;
    bf16x8 mfr[4][4];
    #pragma unroll
    for (int d = 0; d < 4; ++d)
        #pragma unroll
        for (int mt = 0; mt < 4; ++mt)
            mfr[d][mt] = *(const bf16x8*)(mbase + (size_t)mt * 8192 + d * 32);

    asm volatile("s_waitcnt vmcnt(16)" ::: "memory");
    __builtin_amdgcn_s_barrier();
    __builtin_amdgcn_sched_barrier(0);

    f32x4 accR[4][8];
    #pragma unroll
    for (int mt = 0; mt < 4; ++mt)
        #pragma unroll
        for (int nt = 0; nt < 8; ++nt) accR[mt][nt] = (f32x4){0.f, 0.f, 0.f, 0.f};

    #pragma unroll
    for (int kf = 0; kf < 16; ++kf) {
        #pragma unroll
        for (int nh = 0; nh < 2; ++nh) {
            bf16x8 yfr[4];
            #pragma unroll
            for (int n4 = 0; n4 < 4; ++n4) {
                int y = (nh * 4 + n4) * 16 + l15;
                yfr[n4] = *(const bf16x8*)(smem + y * 1024 + (((kf * 4 + l4) ^ (y & 63)) * 16));
            }
            #pragma unroll
            for (int mt = 0; mt < 4; ++mt)
                #pragma unroll
                for (int n4 = 0; n4 < 4; ++n4)
                    accR[mt][nh * 4 + n4] = __builtin_amdgcn_mfma_f32_16x16x32_bf16(
                        mfr[kf & 3][mt], yfr[n4], accR[mt][nh * 4 + n4], 0, 0, 0);
        }
        if (kf < 12) {
            #pragma unroll
            for (int mt = 0; mt < 4; ++mt)
                mfr[kf & 3][mt] = *(const bf16x8*)(mbase + (size_t)mt * 8192 + (kf + 4) * 32);
        }
    }

    const unsigned short* xbase = xbf + (size_t)(b * 128 + xg * 64 + l15) * 512 + l4 * 8;
    bf16x8 xfr[3][4];
    #pragma unroll
    for (int d = 0; d < 3; ++d)
        #pragma unroll
        for (int mt = 0; mt < 4; ++mt)
            xfr[d][mt] = *(const bf16x8*)(xbase + (size_t)mt * 8192 + d * 32);

    asm volatile("s_waitcnt lgkmcnt(0)" ::: "memory");
    __builtin_amdgcn_s_barrier();
    __builtin_amdgcn_sched_barrier(0);

    #pragma unroll
    for (int mt = 0; mt < 4; ++mt)
        #pragma unroll
        for (int nt = 0; nt < 8; ++nt) {
            int y = nt * 16 + l15;
            int chunk = g8 * 8 + mt * 2 + (l4 >> 1);
            int byte = y * 1024 + ((chunk ^ (y & 63)) * 16) + (l4 & 1) * 8;
            unsigned p0 = f2bf(accR[mt][nt][0]) | ((unsigned)f2bf(accR[mt][nt][1]) << 16);
            unsigned p1 = f2bf(accR[mt][nt][2]) | ((unsigned)f2bf(accR[mt][nt][3]) << 16);
            *(uint2*)(smem + byte) = make_uint2(p0, p1);
        }
    asm volatile("s_waitcnt lgkmcnt(0)" ::: "memory");
    __builtin_amdgcn_s_barrier();
    __builtin_amdgcn_sched_barrier(0);

    f32x4 acc[4][2];
    #pragma unroll
    for (int mt = 0; mt < 4; ++mt)
        #pragma unroll
        for (int nt = 0; nt < 2; ++nt) acc[mt][nt] = (f32x4){0.f, 0.f, 0.f, 0.f};

    #pragma unroll
    for (int kf = 0; kf < 16; ++kf) {
        bf16x8 rfr[2];
        #pragma unroll
        for (int nt = 0; nt < 2; ++nt) {
            int y = yg * 32 + nt * 16 + l15;
            rfr[nt] = *(const bf16x8*)(smem + y * 1024 + (((kf * 4 + l4) ^ (y & 63)) * 16));
        }
        #pragma unroll
        for (int mt = 0; mt < 4; ++mt)
            #pragma unroll
            for (int nt = 0; nt < 2; ++nt)
                acc[mt][nt] = __builtin_amdgcn_mfma_f32_16x16x32_bf16(
                    xfr[kf % 3][mt], rfr[nt], acc[mt][nt], 0, 0, 0);
        if (kf < 13) {
            #pragma unroll
            for (int mt = 0; mt < 4; ++mt)
                xfr[kf % 3][mt] = *(const bf16x8*)(xbase + (size_t)mt * 8192 + (kf + 3) * 32);
        }
    }

    float dv = d_arr[bz];
    float* op = out + (size_t)bz * 16384;
    #pragma unroll
    for (int mt = 0; mt < 4; ++mt) {
        float4 uq = *(const float4*)(u_arr + bz * 128 + xg * 64 + mt * 16 + l4 * 4);
        #pragma unroll
        for (int nt = 0; nt < 2; ++nt) {
            int y = yg * 32 + nt * 16 + l15;
            float vv = v_arr[bz * 128 + y] + dv;
            int x0 = xg * 64 + mt * 16 + l4 * 4;
            op[(x0 + 0) * 128 + y] = acc[mt][nt][0] + uq.x + vv;
            op[(x0 + 1) * 128 + y] = acc[mt][nt][1] + uq.y + vv;
            op[(x0 + 2) * 128 + y] = acc[mt][nt][2] + uq.z + vv;
            op[(x0 + 3) * 128 + y] = acc[mt][nt][3] + uq.w + vv;
        }
    }
}

extern "C" void kernel_launch(void* const* d_in, const int* in_sizes, int n_in,
                              void* d_out, int out_size, void* d_ws, size_t ws_size,
                              hipStream_t stream)
{
    const float* x = (const float*)d_in[0];
    const float* y = (const float*)d_in[1];
    const float* z = (const float*)d_in[2];
    const float* w = (const float*)d_in[3];
    float* out = (float*)d_out;
    char* ws = (char*)d_ws;

    unsigned short* xbf = (unsigned short*)(ws + 0);           // 512 KB
    unsigned short* ybf = (unsigned short*)(ws + 524288);      // 512 KB
    unsigned short* zbf = (unsigned short*)(ws + 1048576);     // 512 KB
    float* a_arr = (float*)(ws + 1572864);                     // 1 MB
    float* c_arr = (float*)(ws + 2621440);                     // 1 MB
    float* d_arr = (float*)(ws + 3670016);                     // 2 KB
    float* u_arr = (float*)(ws + 3674112);                     // 256 KB
    float* v_arr = (float*)(ws + 3936256);                     // 256 KB
    unsigned short* Mws = (unsigned short*)(ws + 4198400);     // 268 MB

    hipLaunchKernelGGL(k_cast, dim3(384), dim3(256), 0, stream, x, y, z, xbf, ybf, zbf);
    hipLaunchKernelGGL(k_edge, dim3(136), dim3(256), 0, stream, z, w, a_arr, c_arr, d_arr);
    hipLaunchKernelGGL(k_uv, dim3(512), dim3(512), 0, stream, x, y, a_arr, c_arr, u_arr, v_arr);
    hipLaunchKernelGGL(k_gemm1, dim3(2048), dim3(512), 131072, stream, zbf, w, Mws);
    hipLaunchKernelGGL(k_fuse, dim3(512), dim3(512), 131072, stream, xbf, ybf, Mws,
                       u_arr, v_arr, d_arr, out);
}

// Round 12
// 511.622 us; speedup vs baseline: 1.1234x; 1.1234x over previous
//
#include <hip/hip_runtime.h>
#include <stdint.h>

// Triaffine: out[b,z,x,y] = sum_{i,j,k} xb[x,i] z[z,k] W[i,k,j] yb[y,j]
// B=4, S=128, D=512.  W: [513][512][513] f32 (i,k,j), elem (i,k,j) at (i*512+k)*513+j.
//
//   M[bz,i,j] = sum_k z[bz,k] W[i,k,j]        (i,j < 512)   -- k_gemm1, bf16 out
//   per bz:  R[i,y] = sum_j M[i,j] Ybf[y,j]                  -- k_fuse pass-2
//            out[x,y] = sum_i Xbf[x,i] R[i,y] + u[x]+v[y]+d  -- k_fuse pass-3
//   a[bz,i], c[bz,j], d[bz] from W edges (k_edge); u=x.a, v=y.c (k_uv)

typedef __attribute__((ext_vector_type(8))) short bf16x8;
typedef __attribute__((ext_vector_type(4))) float f32x4;

__device__ __forceinline__ unsigned short f2bf(float f) {
    unsigned int u = __float_as_uint(f);
    u += 0x7fffu + ((u >> 16) & 1u);      // RNE
    return (unsigned short)(u >> 16);
}

__device__ __forceinline__ void gload_lds16(const void* g, void* l) {
    __builtin_amdgcn_global_load_lds((const __attribute__((address_space(1))) void*)g,
                                     (__attribute__((address_space(3))) void*)l, 16, 0, 0);
}

// ---------------- cast x,y,z -> bf16 ----------------
__global__ __launch_bounds__(256) void k_cast(const float* __restrict__ x,
    const float* __restrict__ y, const float* __restrict__ z,
    unsigned short* __restrict__ xbf, unsigned short* __restrict__ ybf,
    unsigned short* __restrict__ zbf)
{
    int t = blockIdx.x * 256 + threadIdx.x;
    int arr = t >> 15;
    int off = (t & 32767) * 8;
    const float* src = (arr == 0) ? x : (arr == 1) ? y : z;
    unsigned short* dst = (arr == 0) ? xbf : (arr == 1) ? ybf : zbf;
    float4 a = *(const float4*)(src + off);
    float4 b = *(const float4*)(src + off + 4);
    uint4 o;
    o.x = f2bf(a.x) | ((unsigned)f2bf(a.y) << 16);
    o.y = f2bf(a.z) | ((unsigned)f2bf(a.w) << 16);
    o.z = f2bf(b.x) | ((unsigned)f2bf(b.y) << 16);
    o.w = f2bf(b.z) | ((unsigned)f2bf(b.w) << 16);
    *(uint4*)(dst + off) = o;
}

// ---------------- bias-edge GEMMs ----------------
__global__ __launch_bounds__(256) void k_edge(const float* __restrict__ z,
    const float* __restrict__ w, float* __restrict__ a_arr,
    float* __restrict__ c_arr, float* __restrict__ d_arr)
{
    __shared__ float Zs[64][33];
    __shared__ float Bs[32][65];
    int t = threadIdx.x;
    int mb = blockIdx.x % 17, bzb = blockIdx.x / 17;
    int tr = t >> 4, tc = t & 15;
    float acc[4][4] = {};
    for (int k0 = 0; k0 < 512; k0 += 32) {
        __syncthreads();
        {   int row = t >> 2, ko = (t & 3) * 8;
            const float* p = z + (bzb * 64 + row) * 512 + k0 + ko;
            float4 v0 = ((const float4*)p)[0], v1 = ((const float4*)p)[1];
            Zs[row][ko + 0] = v0.x; Zs[row][ko + 1] = v0.y; Zs[row][ko + 2] = v0.z; Zs[row][ko + 3] = v0.w;
            Zs[row][ko + 4] = v1.x; Zs[row][ko + 5] = v1.y; Zs[row][ko + 6] = v1.z; Zs[row][ko + 7] = v1.w;
        }
        {   int kr = t >> 3, mo = (t & 7) * 8;
            for (int e = 0; e < 8; ++e) {
                int m = mb * 64 + mo + e;
                float v = 0.f;
                int krow = k0 + kr;
                if (m < 512)        v = w[(m * 512 + krow) * 513 + 512];
                else if (m < 1024)  v = w[(262144 + krow) * 513 + (m - 512)];
                else if (m == 1024) v = w[(262144 + krow) * 513 + 512];
                Bs[kr][mo + e] = v;
            }
        }
        __syncthreads();
        for (int kk = 0; kk < 32; ++kk) {
            float zr[4], br[4];
            for (int r = 0; r < 4; ++r) zr[r] = Zs[tr * 4 + r][kk];
            for (int c = 0; c < 4; ++c) br[c] = Bs[kk][tc * 4 + c];
            for (int r = 0; r < 4; ++r)
                for (int c = 0; c < 4; ++c) acc[r][c] += zr[r] * br[c];
        }
    }
    for (int r = 0; r < 4; ++r)
        for (int c = 0; c < 4; ++c) {
            int bz = bzb * 64 + tr * 4 + r;
            int m = mb * 64 + tc * 4 + c;
            if (m < 512)        a_arr[bz * 512 + m] = acc[r][c];
            else if (m < 1024)  c_arr[bz * 512 + (m - 512)] = acc[r][c];
            else if (m == 1024) d_arr[bz] = acc[r][c];
        }
}

// ---------------- k_uv: u[bz,x] = x.a_bz, v[bz,y] = y.c_bz ----------------
__global__ __launch_bounds__(512) void k_uv(const float* __restrict__ xf,
    const float* __restrict__ yf, const float* __restrict__ a_arr,
    const float* __restrict__ c_arr, float* __restrict__ u_arr,
    float* __restrict__ v_arr)
{
    __shared__ float part[512];
    int bz = blockIdx.x;
    int b = bz >> 7;
    int t = threadIdx.x, r = t >> 2, q = t & 3;
    {
        const float* xp = xf + (size_t)(b * 128 + r) * 512;
        const float* ap = a_arr + bz * 512;
        float s = 0.f;
        #pragma unroll 4
        for (int c0 = 0; c0 < 32; ++c0) {
            int col = c0 * 16 + q * 4;
            float4 xv = *(const float4*)(xp + col);
            float4 av = *(const float4*)(ap + col);
            s += xv.x * av.x + xv.y * av.y + xv.z * av.z + xv.w * av.w;
        }
        part[t] = s;
    }
    __syncthreads();
    if (t < 128) u_arr[bz * 128 + t] = part[t*4] + part[t*4+1] + part[t*4+2] + part[t*4+3];
    __syncthreads();
    {
        const float* yp = yf + (size_t)(b * 128 + r) * 512;
        const float* cp = c_arr + bz * 512;
        float s = 0.f;
        #pragma unroll 4
        for (int c0 = 0; c0 < 32; ++c0) {
            int col = c0 * 16 + q * 4;
            float4 yv = *(const float4*)(yp + col);
            float4 cv = *(const float4*)(cp + col);
            s += yv.x * cv.x + yv.y * cv.y + yv.z * cv.z + yv.w * cv.w;
        }
        part[t] = s;
    }
    __syncthreads();
    if (t < 128) v_arr[bz * 128 + t] = part[t*4] + part[t*4+1] + part[t*4+2] + part[t*4+3];
}

// ---------------- G1 v7: W streamed f32 via global_load_lds ----------------
// BM=512 (all bz; W read once), BN=128, BK=32, 16 steps, 8 waves (4 bzg x 2 jg),
// wave tile 128bz x 64j, acc[8][4]. 1 WG/CU.
// A (Z bf16): gload_lds, pre-swizzled source (round-7 verified mapping).
// B (W f32): gload_lds into [32 k][128 j] f32 tile (COALESCED 16B/lane HBM
//   stream — replaces round-7's strided scalar loads), source pre-swizzle
//   q ^= ((k>>3)&3)<<2; fragments via 8x ds_read_b32 (2-way bank = free) +
//   in-reg f2bf pack.
// m97 2-phase: stage(next) -> compute(cur) -> vmcnt(0)+lgkmcnt(0) barrier
// (staging issued a full compute phase before its wait).
__global__ __launch_bounds__(512, 2) void k_gemm1(const unsigned short* __restrict__ zbf,
    const float* __restrict__ w, unsigned short* __restrict__ Mws)
{
    extern __shared__ unsigned char smem[];
    unsigned char* Zb0 = smem;                 // [512 rows][32 k] bf16 = 32 KB
    unsigned char* Zb1 = smem + 32768;
    unsigned char* Bb0 = smem + 65536;         // [32 k][128 j] f32 = 16 KB
    unsigned char* Bb1 = smem + 81920;         // total 98304

    int nwg = gridDim.x, cpx = nwg >> 3;
    int bid = blockIdx.x;
    int swz = (bid & 7) * cpx + (bid >> 3);    // XCD swizzle (nwg % 8 == 0)
    int iloc = swz >> 2, jb = swz & 3;
    int j0 = jb * 128;
    int t = threadIdx.x, wid = t >> 6, lane = t & 63;
    int bzg = wid >> 1, jg = wid & 1;
    int l15 = lane & 15, l4 = lane >> 4;

    // A staging source (pre-swizzled; round-7 verified)
    int arow = lane >> 2;
    int akc  = (lane & 3) ^ ((lane >> 3) & 3);
    const unsigned short* zbase = zbf + (size_t)(wid * 64 + arow) * 512 + akc * 8;
    int aoff = (bzg * 128 + l15) * 64 + ((l4 ^ ((l15 >> 1) & 3)) * 16);

    // B staging: wave wid owns k-rows [wid*4, wid*4+4) (2 KB); 2 gloads/thread.
    // lane maps idx = g*64+lane -> k_t = wid*4 + (idx>>5), q = idx&31 (16B chunk).
    // source chunk pre-swizzled: q_src = q ^ (((k_t>>3)&3)<<2).
    const float* wbase = w + (size_t)iloc * 262656 + j0;
    int kofs[2], jofs[2];
    #pragma unroll
    for (int g = 0; g < 2; ++g) {
        int idx = g * 64 + lane;
        int k_t = wid * 4 + (idx >> 5);
        int q = idx & 31;
        int q_src = q ^ (((k_t >> 3) & 3) << 2);
        kofs[g] = k_t;
        jofs[g] = q_src * 4;
    }
    // B fragment read: per nt, j = jg*64+nt*16+l15; e: k=l4*8+e;
    // byte = k*512 + ((j>>2)^(l4<<2))*16 + (j&3)*4  (2-way banks, free)
    int bjq[4];
    #pragma unroll
    for (int nt = 0; nt < 4; ++nt) {
        int j = jg * 64 + nt * 16 + l15;
        bjq[nt] = (((j >> 2) ^ (l4 << 2)) * 16) + ((j & 3) * 4) + (l4 * 8) * 512;
    }

    f32x4 acc[8][4];
    #pragma unroll
    for (int mt = 0; mt < 8; ++mt)
        #pragma unroll
        for (int nt = 0; nt < 4; ++nt) acc[mt][nt] = (f32x4){0.f, 0.f, 0.f, 0.f};

#define STAGE_A(buf, ks1) { \
    _Pragma("unroll") for (int q = 0; q < 4; ++q) \
        gload_lds16(zbase + (ks1) * 32 + q * 8192, (buf) + wid * 4096 + q * 1024); }
#define STAGE_B(buf, ks1) { \
    _Pragma("unroll") for (int g = 0; g < 2; ++g) \
        gload_lds16(wbase + (size_t)((ks1) * 32 + kofs[g]) * 513 + jofs[g], \
                    (buf) + wid * 2048 + g * 1024); }

    // ---- prologue ----
    STAGE_A(Zb0, 0);
    STAGE_B(Bb0, 0);
    asm volatile("s_waitcnt vmcnt(0)" ::: "memory");
    __builtin_amdgcn_s_barrier();
    __builtin_amdgcn_sched_barrier(0);

    #pragma unroll
    for (int ks = 0; ks < 16; ++ks) {
        const int cur = ks & 1;
        unsigned char* Zcur  = cur ? Zb1 : Zb0;
        unsigned char* Znext = cur ? Zb0 : Zb1;
        unsigned char* Bcur  = cur ? Bb1 : Bb0;
        unsigned char* Bnext = cur ? Bb0 : Bb1;

        // 1. issue next-step staging (in flight under all of compute)
        if (ks < 15) {
            STAGE_A(Znext, ks + 1);
            STAGE_B(Bnext, ks + 1);
        }
        // 2. build B fragments: 8x ds_read_b32 f32 + f2bf pack, per nt
        bf16x8 bfr[4];
        #pragma unroll
        for (int nt = 0; nt < 4; ++nt) {
            float bfv[8];
            #pragma unroll
            for (int e = 0; e < 8; ++e)
                bfv[e] = *(const float*)(Bcur + bjq[nt] + e * 512);
            union { unsigned u[4]; bf16x8 v; } pk;
            pk.u[0] = f2bf(bfv[0]) | ((unsigned)f2bf(bfv[1]) << 16);
            pk.u[1] = f2bf(bfv[2]) | ((unsigned)f2bf(bfv[3]) << 16);
            pk.u[2] = f2bf(bfv[4]) | ((unsigned)f2bf(bfv[5]) << 16);
            pk.u[3] = f2bf(bfv[6]) | ((unsigned)f2bf(bfv[7]) << 16);
            bfr[nt] = pk.v;
        }
        // 3. MFMA over 8 A-frags x 4 B-frags
        #pragma unroll
        for (int mt = 0; mt < 8; ++mt) {
            bf16x8 afr = *(const bf16x8*)(Zcur + aoff + mt * 1024);
            #pragma unroll
            for (int nt = 0; nt < 4; ++nt)
                acc[mt][nt] = __builtin_amdgcn_mfma_f32_16x16x32_bf16(afr, bfr[nt], acc[mt][nt], 0, 0, 0);
        }
        // 4. publish next buffers
        if (ks < 15) {
            asm volatile("s_waitcnt vmcnt(0) lgkmcnt(0)" ::: "memory");
            __builtin_amdgcn_s_barrier();
            __builtin_amdgcn_sched_barrier(0);
        }
    }
#undef STAGE_A
#undef STAGE_B

    // ---- epilogue: store M[bz][iloc][j] bf16 ----
    #pragma unroll
    for (int mt = 0; mt < 8; ++mt)
        #pragma unroll
        for (int nt = 0; nt < 4; ++nt)
            #pragma unroll
            for (int r = 0; r < 4; ++r) {
                int bz = bzg * 128 + mt * 16 + l4 * 4 + r;
                int j  = j0 + jg * 64 + nt * 16 + l15;
                Mws[(size_t)bz * 262144 + (size_t)iloc * 512 + j] = f2bf(acc[mt][nt][r]);
            }
}

// ---------------- G2 v5 (round-10 best, unchanged) ----------------
__global__ __launch_bounds__(512, 2) void k_fuse(const unsigned short* __restrict__ xbf,
    const unsigned short* __restrict__ ybf, const unsigned short* __restrict__ Mws,
    const float* __restrict__ u_arr, const float* __restrict__ v_arr,
    const float* __restrict__ d_arr, float* __restrict__ out)
{
    extern __shared__ unsigned char smem[];    // 131072: Y, later reused as R

    int bid = blockIdx.x;
    int bz = (bid & 7) * 64 + (bid >> 3);      // XCD swizzle (512 = 8*64)
    int b = bz >> 7;
    int t = threadIdx.x, wid = t >> 6, lane = t & 63;
    int l15 = lane & 15, l4 = lane >> 4;
    int xg = wid >> 2, yg = wid & 3;
    int g8 = wid;

    const unsigned short* ybase = ybf + (size_t)(b * 128) * 512;
    #pragma unroll
    for (int it = 0; it < 16; ++it) {
        int row = it * 8 + wid;
        gload_lds16(ybase + (size_t)row * 512 + ((lane ^ (row & 63)) * 8),
                    smem + it * 8192 + t * 16);
    }

    const unsigned short* mbase = Mws + (size_t)bz * 262144
                                + (size_t)(g8 * 64 + l15) * 512 + l4 * 8;
    bf16x8 mfr[4][4];
    #pragma unroll
    for (int d = 0; d < 4; ++d)
        #pragma unroll
        for (int mt = 0; mt < 4; ++mt)
            mfr[d][mt] = *(const bf16x8*)(mbase + (size_t)mt * 8192 + d * 32);

    asm volatile("s_waitcnt vmcnt(16)" ::: "memory");
    __builtin_amdgcn_s_barrier();
    __builtin_amdgcn_sched_barrier(0);

    f32x4 accR[4][8];
    #pragma unroll
    for (int mt = 0; mt < 4; ++mt)
        #pragma unroll
        for (int nt = 0; nt < 8; ++nt) accR[mt][nt] = (f32x4){0.f, 0.f, 0.f, 0.f};

    #pragma unroll
    for (int kf = 0; kf < 16; ++kf) {
        #pragma unroll
        for (int nh = 0; nh < 2; ++nh) {
            bf16x8 yfr[4];
            #pragma unroll
            for (int n4 = 0; n4 < 4; ++n4) {
                int y = (nh * 4 + n4) * 16 + l15;
                yfr[n4] = *(const bf16x8*)(smem + y * 1024 + (((kf * 4 + l4) ^ (y & 63)) * 16));
            }
            #pragma unroll
            for (int mt = 0; mt < 4; ++mt)
                #pragma unroll
                for (int n4 = 0; n4 < 4; ++n4)
                    accR[mt][nh * 4 + n4] = __builtin_amdgcn_mfma_f32_16x16x32_bf16(
                        mfr[kf & 3][mt], yfr[n4], accR[mt][nh * 4 + n4], 0, 0, 0);
        }
        if (kf < 12) {
            #pragma unroll
            for (int mt = 0; mt < 4; ++mt)
                mfr[kf & 3][mt] = *(const bf16x8*)(mbase + (size_t)mt * 8192 + (kf + 4) * 32);
        }
    }

    const unsigned short* xbase = xbf + (size_t)(b * 128 + xg * 64 + l15) * 512 + l4 * 8;
    bf16x8 xfr[3][4];
    #pragma unroll
    for (int d = 0; d < 3; ++d)
        #pragma unroll
        for (int mt = 0; mt < 4; ++mt)
            xfr[d][mt] = *(const bf16x8*)(xbase + (size_t)mt * 8192 + d * 32);

    asm volatile("s_waitcnt lgkmcnt(0)" ::: "memory");
    __builtin_amdgcn_s_barrier();
    __builtin_amdgcn_sched_barrier(0);

    #pragma unroll
    for (int mt = 0; mt < 4; ++mt)
        #pragma unroll
        for (int nt = 0; nt < 8; ++nt) {
            int y = nt * 16 + l15;
            int chunk = g8 * 8 + mt * 2 + (l4 >> 1);
            int byte = y * 1024 + ((chunk ^ (y & 63)) * 16) + (l4 & 1) * 8;
            unsigned p0 = f2bf(accR[mt][nt][0]) | ((unsigned)f2bf(accR[mt][nt][1]) << 16);
            unsigned p1 = f2bf(accR[mt][nt][2]) | ((unsigned)f2bf(accR[mt][nt][3]) << 16);
            *(uint2*)(smem + byte) = make_uint2(p0, p1);
        }
    asm volatile("s_waitcnt lgkmcnt(0)" ::: "memory");
    __builtin_amdgcn_s_barrier();
    __builtin_amdgcn_sched_barrier(0);

    f32x4 acc[4][2];
    #pragma unroll
    for (int mt = 0; mt < 4; ++mt)
        #pragma unroll
        for (int nt = 0; nt < 2; ++nt) acc[mt][nt] = (f32x4){0.f, 0.f, 0.f, 0.f};

    #pragma unroll
    for (int kf = 0; kf < 16; ++kf) {
        bf16x8 rfr[2];
        #pragma unroll
        for (int nt = 0; nt < 2; ++nt) {
            int y = yg * 32 + nt * 16 + l15;
            rfr[nt] = *(const bf16x8*)(smem + y * 1024 + (((kf * 4 + l4) ^ (y & 63)) * 16));
        }
        #pragma unroll
        for (int mt = 0; mt < 4; ++mt)
            #pragma unroll
            for (int nt = 0; nt < 2; ++nt)
                acc[mt][nt] = __builtin_amdgcn_mfma_f32_16x16x32_bf16(
                    xfr[kf % 3][mt], rfr[nt], acc[mt][nt], 0, 0, 0);
        if (kf < 13) {
            #pragma unroll
            for (int mt = 0; mt < 4; ++mt)
                xfr[kf % 3][mt] = *(const bf16x8*)(xbase + (size_t)mt * 8192 + (kf + 3) * 32);
        }
    }

    float dv = d_arr[bz];
    float* op = out + (size_t)bz * 16384;
    #pragma unroll
    for (int mt = 0; mt < 4; ++mt) {
        float4 uq = *(const float4*)(u_arr + bz * 128 + xg * 64 + mt * 16 + l4 * 4);
        #pragma unroll
        for (int nt = 0; nt < 2; ++nt) {
            int y = yg * 32 + nt * 16 + l15;
            float vv = v_arr[bz * 128 + y] + dv;
            int x0 = xg * 64 + mt * 16 + l4 * 4;
            op[(x0 + 0) * 128 + y] = acc[mt][nt][0] + uq.x + vv;
            op[(x0 + 1) * 128 + y] = acc[mt][nt][1] + uq.y + vv;
            op[(x0 + 2) * 128 + y] = acc[mt][nt][2] + uq.z + vv;
            op[(x0 + 3) * 128 + y] = acc[mt][nt][3] + uq.w + vv;
        }
    }
}

extern "C" void kernel_launch(void* const* d_in, const int* in_sizes, int n_in,
                              void* d_out, int out_size, void* d_ws, size_t ws_size,
                              hipStream_t stream)
{
    const float* x = (const float*)d_in[0];
    const float* y = (const float*)d_in[1];
    const float* z = (const float*)d_in[2];
    const float* w = (const float*)d_in[3];
    float* out = (float*)d_out;
    char* ws = (char*)d_ws;

    unsigned short* xbf = (unsigned short*)(ws + 0);           // 512 KB
    unsigned short* ybf = (unsigned short*)(ws + 524288);      // 512 KB
    unsigned short* zbf = (unsigned short*)(ws + 1048576);     // 512 KB
    float* a_arr = (float*)(ws + 1572864);                     // 1 MB
    float* c_arr = (float*)(ws + 2621440);                     // 1 MB
    float* d_arr = (float*)(ws + 3670016);                     // 2 KB
    float* u_arr = (float*)(ws + 3674112);                     // 256 KB
    float* v_arr = (float*)(ws + 3936256);                     // 256 KB
    unsigned short* Mws = (unsigned short*)(ws + 4198400);     // 268 MB

    hipLaunchKernelGGL(k_cast, dim3(384), dim3(256), 0, stream, x, y, z, xbf, ybf, zbf);
    hipLaunchKernelGGL(k_edge, dim3(136), dim3(256), 0, stream, z, w, a_arr, c_arr, d_arr);
    hipLaunchKernelGGL(k_uv, dim3(512), dim3(512), 0, stream, x, y, a_arr, c_arr, u_arr, v_arr);
    hipLaunchKernelGGL(k_gemm1, dim3(2048), dim3(512), 98304, stream, zbf, w, Mws);
    hipLaunchKernelGGL(k_fuse, dim3(512), dim3(512), 131072, stream, xbf, ybf, Mws,
                       u_arr, v_arr, d_arr, out);
}